// Round 1
// baseline (180.370 us; speedup 1.0000x reference)
//
#include <hip/hip_runtime.h>

#define LN_EPS 1e-5f
#define DD 128
#define TWO_D 256
#define HH 64
#define ROW_STRIDE 68  // 64 p-values + sum + sumsq + 2 pad (272B = 17*16B, keeps float4 alignment)

// ---------------- kernel 0: G[h] = sum_d gamma[d]*W1[d][h]; B1c[h] = b1[h] + sum_d beta[d]*W1[d][h]
__global__ void k_prep(const float* __restrict__ gamma, const float* __restrict__ beta,
                       const float* __restrict__ W1, const float* __restrict__ b1,
                       float* __restrict__ ws) {
    int h = threadIdx.x;  // 64 threads
    float g = 0.f, bc = b1[h];
    for (int d = 0; d < TWO_D; ++d) {
        float w = W1[d * HH + h];
        g = fmaf(gamma[d], w, g);
        bc = fmaf(beta[d], w, bc);
    }
    ws[h] = g;
    ws[64 + h] = bc;
}

// ---------------- kernel 1: table[r][h] = sum_d feat[r][d] * gamma[gofs+d] * W1[gofs+d][h]
// Block: 256 threads. Tile: 128 rows x 64 h. Thread: 8 rows x 4 h.
__global__ __launch_bounds__(256) void k_proj(const float* __restrict__ feat, int nrows,
                                              const float* __restrict__ gamma,
                                              const float* __restrict__ W1, int gofs,
                                              float* __restrict__ table) {
    __shared__ float gw[DD * HH];  // 32 KB
    int tid = threadIdx.x;
    for (int i = tid; i < DD * HH; i += 256) {
        int d = i >> 6, h = i & 63;
        gw[i] = gamma[gofs + d] * W1[(gofs + d) * HH + h];
    }
    __syncthreads();

    int hg = tid & 15, rg = tid >> 4;
    int h0 = hg * 4;
    int rbase = blockIdx.x * 128 + rg * 8;

    float acc[8][4];
#pragma unroll
    for (int i = 0; i < 8; ++i)
#pragma unroll
        for (int k = 0; k < 4; ++k) acc[i][k] = 0.f;

    int rows[8];
#pragma unroll
    for (int i = 0; i < 8; ++i) {
        int r = rbase + i;
        rows[i] = r < nrows ? r : (nrows - 1);  // clamp for OOB loads, writes guarded below
    }

    for (int d0 = 0; d0 < DD; d0 += 4) {
        float4 g0 = *(const float4*)&gw[(d0 + 0) * HH + h0];
        float4 g1 = *(const float4*)&gw[(d0 + 1) * HH + h0];
        float4 g2 = *(const float4*)&gw[(d0 + 2) * HH + h0];
        float4 g3 = *(const float4*)&gw[(d0 + 3) * HH + h0];
#pragma unroll
        for (int i = 0; i < 8; ++i) {
            float4 a = *(const float4*)&feat[(size_t)rows[i] * DD + d0];
            acc[i][0] = fmaf(a.x, g0.x, acc[i][0]);
            acc[i][1] = fmaf(a.x, g0.y, acc[i][1]);
            acc[i][2] = fmaf(a.x, g0.z, acc[i][2]);
            acc[i][3] = fmaf(a.x, g0.w, acc[i][3]);
            acc[i][0] = fmaf(a.y, g1.x, acc[i][0]);
            acc[i][1] = fmaf(a.y, g1.y, acc[i][1]);
            acc[i][2] = fmaf(a.y, g1.z, acc[i][2]);
            acc[i][3] = fmaf(a.y, g1.w, acc[i][3]);
            acc[i][0] = fmaf(a.z, g2.x, acc[i][0]);
            acc[i][1] = fmaf(a.z, g2.y, acc[i][1]);
            acc[i][2] = fmaf(a.z, g2.z, acc[i][2]);
            acc[i][3] = fmaf(a.z, g2.w, acc[i][3]);
            acc[i][0] = fmaf(a.w, g3.x, acc[i][0]);
            acc[i][1] = fmaf(a.w, g3.y, acc[i][1]);
            acc[i][2] = fmaf(a.w, g3.z, acc[i][2]);
            acc[i][3] = fmaf(a.w, g3.w, acc[i][3]);
        }
    }

#pragma unroll
    for (int i = 0; i < 8; ++i) {
        int r = rbase + i;
        if (r < nrows) {
            *(float4*)&table[(size_t)r * ROW_STRIDE + h0] =
                make_float4(acc[i][0], acc[i][1], acc[i][2], acc[i][3]);
        }
    }
}

// ---------------- kernel 2: per-row sum and sum of squares -> table[r][64], table[r][65]
// 16 lanes per row, float4 loads.
__global__ __launch_bounds__(256) void k_sums(const float* __restrict__ feat, int nrows,
                                              float* __restrict__ table) {
    int gtid = blockIdx.x * 256 + threadIdx.x;
    int l = gtid & 15;
    int row = gtid >> 4;
    float s = 0.f, q = 0.f;
    if (row < nrows) {
        const float* fr = feat + (size_t)row * DD;
        float4 a = *(const float4*)&fr[l * 4];
        float4 b = *(const float4*)&fr[64 + l * 4];
        s = a.x + a.y + a.z + a.w + b.x + b.y + b.z + b.w;
        q = a.x * a.x + a.y * a.y + a.z * a.z + a.w * a.w +
            b.x * b.x + b.y * b.y + b.z * b.z + b.w * b.w;
    }
#pragma unroll
    for (int m = 1; m < 16; m <<= 1) {
        s += __shfl_xor(s, m);
        q += __shfl_xor(q, m);
    }
    if (row < nrows && l == 0) {
        *(float2*)&table[(size_t)row * ROW_STRIDE + 64] = make_float2(s, q);
    }
}

// ---------------- kernel 3: per-pair fused LN+MLP via precomputed tables
// 16 lanes per pair; lane l holds h = 4l..4l+3.
__global__ __launch_bounds__(256) void k_pairs(const int* __restrict__ node_idx,
                                               const int* __restrict__ edge_idx,
                                               const float* __restrict__ node_table,
                                               const float* __restrict__ edge_table,
                                               const float* __restrict__ Gv,
                                               const float* __restrict__ Bv,
                                               const float* __restrict__ W2,
                                               const float* __restrict__ b2,
                                               float* __restrict__ out, int E) {
    int gtid = blockIdx.x * 256 + threadIdx.x;
    int l = gtid & 15;
    int grp = gtid >> 4;
    int ngrps = (gridDim.x * 256) >> 4;

    float4 G4 = *(const float4*)&Gv[l * 4];
    float4 B4 = *(const float4*)&Bv[l * 4];
    float4 w2 = *(const float4*)&W2[l * 4];
    float b2v = b2[0];

    for (int p = grp; p < E; p += ngrps) {
        int ni = node_idx[p];
        int ei = edge_idx[p];
        const float* er = edge_table + (size_t)ei * ROW_STRIDE;
        const float* nr = node_table + (size_t)ni * ROW_STRIDE;
        float4 pe = *(const float4*)&er[l * 4];
        float4 pn = *(const float4*)&nr[l * 4];
        float2 se = *(const float2*)&er[64];
        float2 sn = *(const float2*)&nr[64];

        float S = se.x + sn.x;
        float Q = se.y + sn.y;
        float mu = S * (1.f / TWO_D);
        float var = fmaf(Q, 1.f / TWO_D, -mu * mu);
        float rstd = rsqrtf(var + LN_EPS);

        float v0 = fmaf(rstd, (pe.x + pn.x) - mu * G4.x, B4.x);
        float v1 = fmaf(rstd, (pe.y + pn.y) - mu * G4.y, B4.y);
        float v2 = fmaf(rstd, (pe.z + pn.z) - mu * G4.z, B4.z);
        float v3 = fmaf(rstd, (pe.w + pn.w) - mu * G4.w, B4.w);
        v0 = fmaxf(v0, 0.f);
        v1 = fmaxf(v1, 0.f);
        v2 = fmaxf(v2, 0.f);
        v3 = fmaxf(v3, 0.f);
        float acc = v0 * w2.x + v1 * w2.y + v2 * w2.z + v3 * w2.w;

        acc += __shfl_xor(acc, 1);
        acc += __shfl_xor(acc, 2);
        acc += __shfl_xor(acc, 4);
        acc += __shfl_xor(acc, 8);

        if (l == 0) out[p] = acc + b2v;
    }
}

extern "C" void kernel_launch(void* const* d_in, const int* in_sizes, int n_in,
                              void* d_out, int out_size, void* d_ws, size_t ws_size,
                              hipStream_t stream) {
    const float* node_feat = (const float*)d_in[0];
    const float* edge_feat = (const float*)d_in[1];
    const float* gamma = (const float*)d_in[2];
    const float* beta = (const float*)d_in[3];
    const float* W1 = (const float*)d_in[4];
    const float* b1 = (const float*)d_in[5];
    const float* W2 = (const float*)d_in[6];
    const float* b2 = (const float*)d_in[7];
    const int* node_idx = (const int*)d_in[8];
    const int* edge_idx = (const int*)d_in[9];

    int n_nodes = in_sizes[0] / DD;
    int n_edges = in_sizes[1] / DD;
    int E = in_sizes[8];

    float* ws = (float*)d_ws;
    float* G = ws;
    float* B1c = ws + 64;
    float* node_table = ws + 128;                               // 16B-aligned
    float* edge_table = node_table + (size_t)n_nodes * ROW_STRIDE;
    // total ws: (128 + 68*(n_nodes+n_edges))*4 B ~= 32.7 MB

    k_prep<<<1, 64, 0, stream>>>(gamma, beta, W1, b1, ws);
    k_proj<<<(n_edges + 127) / 128, 256, 0, stream>>>(edge_feat, n_edges, gamma, W1, 0, edge_table);
    k_proj<<<(n_nodes + 127) / 128, 256, 0, stream>>>(node_feat, n_nodes, gamma, W1, 128, node_table);
    k_sums<<<(n_edges + 15) / 16, 256, 0, stream>>>(edge_feat, n_edges, edge_table);
    k_sums<<<(n_nodes + 15) / 16, 256, 0, stream>>>(node_feat, n_nodes, node_table);
    k_pairs<<<2048, 256, 0, stream>>>(node_idx, edge_idx, node_table, edge_table,
                                      G, B1c, W2, b2, (float*)d_out, E);
}

// Round 2
// 111.642 us; speedup vs baseline: 1.6156x; 1.6156x over previous
//
#include <hip/hip_runtime.h>

#define LN_EPS 1e-5f
#define DD 128
#define TWO_D 256
#define HH 64

typedef unsigned int uint;

__device__ __forceinline__ unsigned short f2bf(float f) {
    uint u = __float_as_uint(f);
    u += 0x7FFFu + ((u >> 16) & 1u);  // round-to-nearest-even
    return (unsigned short)(u >> 16);
}

// ---------------- kernel 0: G[h] = sum_d gamma[d]*W1[d][h]; B1c[h] = b1[h] + sum_d beta[d]*W1[d][h]
__global__ void k_prep(const float* __restrict__ gamma, const float* __restrict__ beta,
                       const float* __restrict__ W1, const float* __restrict__ b1,
                       float* __restrict__ ws) {
    int h = threadIdx.x;  // 64 threads
    float g = 0.f, bc = b1[h];
    for (int d = 0; d < TWO_D; ++d) {
        float w = W1[d * HH + h];
        g = fmaf(gamma[d], w, g);
        bc = fmaf(beta[d], w, bc);
    }
    ws[h] = g;
    ws[64 + h] = bc;
}

// ---------------- kernel 1: ptable[r][h] = bf16( sum_d feat[r][d]*gamma[gofs+d]*W1[gofs+d][h] )
//                  + phase 2: sums[r] = (sum_d feat[r][d], sum_d feat[r][d]^2)
// Block: 256 threads. Tile: 128 rows x 64 h. Thread: 8 rows x 4 h.
__global__ __launch_bounds__(256) void k_proj(const float* __restrict__ feat, int nrows,
                                              const float* __restrict__ gamma,
                                              const float* __restrict__ W1, int gofs,
                                              unsigned short* __restrict__ ptable,
                                              float2* __restrict__ sums) {
    __shared__ float gw[DD * HH];  // 32 KB
    int tid = threadIdx.x;
    for (int i = tid; i < DD * HH; i += 256) {
        int d = i >> 6, h = i & 63;
        gw[i] = gamma[gofs + d] * W1[(gofs + d) * HH + h];
    }
    __syncthreads();

    int hg = tid & 15, rg = tid >> 4;
    int h0 = hg * 4;
    int rbase = blockIdx.x * 128 + rg * 8;

    float acc[8][4];
#pragma unroll
    for (int i = 0; i < 8; ++i)
#pragma unroll
        for (int k = 0; k < 4; ++k) acc[i][k] = 0.f;

    int rows[8];
#pragma unroll
    for (int i = 0; i < 8; ++i) {
        int r = rbase + i;
        rows[i] = r < nrows ? r : (nrows - 1);  // clamp for OOB loads, writes guarded below
    }

    for (int d0 = 0; d0 < DD; d0 += 4) {
        float4 g0 = *(const float4*)&gw[(d0 + 0) * HH + h0];
        float4 g1 = *(const float4*)&gw[(d0 + 1) * HH + h0];
        float4 g2 = *(const float4*)&gw[(d0 + 2) * HH + h0];
        float4 g3 = *(const float4*)&gw[(d0 + 3) * HH + h0];
#pragma unroll
        for (int i = 0; i < 8; ++i) {
            float4 a = *(const float4*)&feat[(size_t)rows[i] * DD + d0];
            acc[i][0] = fmaf(a.x, g0.x, acc[i][0]);
            acc[i][1] = fmaf(a.x, g0.y, acc[i][1]);
            acc[i][2] = fmaf(a.x, g0.z, acc[i][2]);
            acc[i][3] = fmaf(a.x, g0.w, acc[i][3]);
            acc[i][0] = fmaf(a.y, g1.x, acc[i][0]);
            acc[i][1] = fmaf(a.y, g1.y, acc[i][1]);
            acc[i][2] = fmaf(a.y, g1.z, acc[i][2]);
            acc[i][3] = fmaf(a.y, g1.w, acc[i][3]);
            acc[i][0] = fmaf(a.z, g2.x, acc[i][0]);
            acc[i][1] = fmaf(a.z, g2.y, acc[i][1]);
            acc[i][2] = fmaf(a.z, g2.z, acc[i][2]);
            acc[i][3] = fmaf(a.z, g2.w, acc[i][3]);
            acc[i][0] = fmaf(a.w, g3.x, acc[i][0]);
            acc[i][1] = fmaf(a.w, g3.y, acc[i][1]);
            acc[i][2] = fmaf(a.w, g3.z, acc[i][2]);
            acc[i][3] = fmaf(a.w, g3.w, acc[i][3]);
        }
    }

#pragma unroll
    for (int i = 0; i < 8; ++i) {
        int r = rbase + i;
        if (r < nrows) {
            ushort4 st;
            st.x = f2bf(acc[i][0]);
            st.y = f2bf(acc[i][1]);
            st.z = f2bf(acc[i][2]);
            st.w = f2bf(acc[i][3]);
            *(ushort4*)&ptable[(size_t)r * HH + h0] = st;
        }
    }

    // ---- phase 2: per-row sum / sumsq (rows are hot in L2 from phase 1)
    int l = tid & 15, rg2 = tid >> 4;
#pragma unroll
    for (int k = 0; k < 8; ++k) {
        int r = blockIdx.x * 128 + rg2 + k * 16;
        float s = 0.f, q = 0.f;
        if (r < nrows) {
            const float* fr = feat + (size_t)r * DD;
            float4 a = *(const float4*)&fr[l * 4];
            float4 b = *(const float4*)&fr[64 + l * 4];
            s = a.x + a.y + a.z + a.w + b.x + b.y + b.z + b.w;
            q = a.x * a.x + a.y * a.y + a.z * a.z + a.w * a.w +
                b.x * b.x + b.y * b.y + b.z * b.z + b.w * b.w;
        }
#pragma unroll
        for (int m = 1; m < 16; m <<= 1) {
            s += __shfl_xor(s, m);
            q += __shfl_xor(q, m);
        }
        if (r < nrows && l == 0) sums[r] = make_float2(s, q);
    }
}

// ---------------- kernel 2: per-pair fused LN+MLP via precomputed bf16 tables
// 8 lanes per pair; lane l holds h = 8l..8l+7 (one 16B uint4 = 8 bf16).
__global__ __launch_bounds__(256) void k_pairs(const int* __restrict__ node_idx,
                                               const int* __restrict__ edge_idx,
                                               const unsigned short* __restrict__ node_pt,
                                               const unsigned short* __restrict__ edge_pt,
                                               const float2* __restrict__ node_sums,
                                               const float2* __restrict__ edge_sums,
                                               const float* __restrict__ Gv,
                                               const float* __restrict__ Bv,
                                               const float* __restrict__ W2,
                                               const float* __restrict__ b2,
                                               float* __restrict__ out, int E) {
    int gtid = blockIdx.x * 256 + threadIdx.x;
    int l = gtid & 7;
    int grp = gtid >> 3;
    int ngrps = (gridDim.x * 256) >> 3;

    float G8[8], B8[8], W8[8];
#pragma unroll
    for (int j = 0; j < 8; ++j) {
        G8[j] = Gv[l * 8 + j];
        B8[j] = Bv[l * 8 + j];
        W8[j] = W2[l * 8 + j];
    }
    float b2v = b2[0];

    for (int p = grp; p < E; p += ngrps) {
        int ni = node_idx[p];
        int ei = edge_idx[p];
        uint4 ue = *(const uint4*)&edge_pt[(size_t)ei * HH + l * 8];
        uint4 un = *(const uint4*)&node_pt[(size_t)ni * HH + l * 8];
        float2 se = edge_sums[ei];
        float2 sn = node_sums[ni];

        float S = se.x + sn.x;
        float Q = se.y + sn.y;
        float mu = S * (1.f / TWO_D);
        float var = fmaf(Q, 1.f / TWO_D, -mu * mu);
        float rstd = rsqrtf(var + LN_EPS);
        float nmu = -mu;

        uint ue_[4] = {ue.x, ue.y, ue.z, ue.w};
        uint un_[4] = {un.x, un.y, un.z, un.w};
        float acc = 0.f;
#pragma unroll
        for (int j = 0; j < 4; ++j) {
            float pe0 = __uint_as_float(ue_[j] << 16);
            float pe1 = __uint_as_float(ue_[j] & 0xFFFF0000u);
            float pn0 = __uint_as_float(un_[j] << 16);
            float pn1 = __uint_as_float(un_[j] & 0xFFFF0000u);
            float t0 = fmaf(nmu, G8[2 * j], pe0 + pn0);
            float v0 = fmaf(rstd, t0, B8[2 * j]);
            v0 = fmaxf(v0, 0.f);
            acc = fmaf(v0, W8[2 * j], acc);
            float t1 = fmaf(nmu, G8[2 * j + 1], pe1 + pn1);
            float v1 = fmaf(rstd, t1, B8[2 * j + 1]);
            v1 = fmaxf(v1, 0.f);
            acc = fmaf(v1, W8[2 * j + 1], acc);
        }

        acc += __shfl_xor(acc, 1);
        acc += __shfl_xor(acc, 2);
        acc += __shfl_xor(acc, 4);

        if (l == 0) out[p] = acc + b2v;
    }
}

extern "C" void kernel_launch(void* const* d_in, const int* in_sizes, int n_in,
                              void* d_out, int out_size, void* d_ws, size_t ws_size,
                              hipStream_t stream) {
    const float* node_feat = (const float*)d_in[0];
    const float* edge_feat = (const float*)d_in[1];
    const float* gamma = (const float*)d_in[2];
    const float* beta = (const float*)d_in[3];
    const float* W1 = (const float*)d_in[4];
    const float* b1 = (const float*)d_in[5];
    const float* W2 = (const float*)d_in[6];
    const float* b2 = (const float*)d_in[7];
    const int* node_idx = (const int*)d_in[8];
    const int* edge_idx = (const int*)d_in[9];

    int n_nodes = in_sizes[0] / DD;
    int n_edges = in_sizes[1] / DD;
    int E = in_sizes[8];

    float* ws = (float*)d_ws;
    float* G = ws;
    float* B1c = ws + 64;
    float2* node_sums = (float2*)(ws + 128);
    float2* edge_sums = node_sums + n_nodes;

    size_t off = 128 + 2 * (size_t)n_nodes + 2 * (size_t)n_edges;
    off = (off + 31) & ~(size_t)31;  // 128B alignment for ptable rows
    unsigned short* node_pt = (unsigned short*)(ws + off);
    unsigned short* edge_pt = node_pt + (size_t)n_nodes * HH;
    // total ws ~= 0.96 MB sums + 15.4 MB tables ~= 16.4 MB

    k_prep<<<1, 64, 0, stream>>>(gamma, beta, W1, b1, ws);
    k_proj<<<(n_edges + 127) / 128, 256, 0, stream>>>(edge_feat, n_edges, gamma, W1, 0,
                                                      edge_pt, edge_sums);
    k_proj<<<(n_nodes + 127) / 128, 256, 0, stream>>>(node_feat, n_nodes, gamma, W1, 128,
                                                      node_pt, node_sums);
    k_pairs<<<2048, 256, 0, stream>>>(node_idx, edge_idx, node_pt, edge_pt,
                                      node_sums, edge_sums, G, B1c, W2, b2,
                                      (float*)d_out, E);
}

// Round 4
// 85.293 us; speedup vs baseline: 2.1147x; 1.3089x over previous
//
#include <hip/hip_runtime.h>

#define LN_EPS 1e-5f
#define DD 128
#define TWO_D 256
#define HH 64

typedef unsigned int uint;

__device__ __forceinline__ unsigned short f2bf(float f) {
    uint u = __float_as_uint(f);
    u += 0x7FFFu + ((u >> 16) & 1u);  // round-to-nearest-even
    return (unsigned short)(u >> 16);
}

// ---------------- fused: block 0 = prep (G, B1c); blocks [1,nbN] = node proj;
//                  blocks (nbN, nbN+nbE] = edge proj. Each proj block: 128 rows.
__global__ __launch_bounds__(256) void k_fused(
    const float* __restrict__ node_feat, int n_nodes, int nbN,
    const float* __restrict__ edge_feat, int n_edges,
    const float* __restrict__ gamma, const float* __restrict__ beta,
    const float* __restrict__ W1, const float* __restrict__ b1,
    unsigned short* __restrict__ node_pt, float2* __restrict__ node_sums,
    unsigned short* __restrict__ edge_pt, float2* __restrict__ edge_sums,
    float* __restrict__ GB) {
    int bid = blockIdx.x;
    int tid = threadIdx.x;

    if (bid == 0) {
        // prep: GB[0..63] = gamma @ W1 ; GB[64..127] = b1 + beta @ W1
        if (tid < 128) {
            int h = tid & 63;
            bool isB = tid >= 64;
            float acc = isB ? b1[h] : 0.f;
            const float* coef = isB ? beta : gamma;
#pragma unroll 8
            for (int d = 0; d < TWO_D; ++d)
                acc = fmaf(coef[d], W1[d * HH + h], acc);
            GB[tid] = acc;
        }
        return;
    }

    const float* feat;
    int nrows, gofs, rbase0;
    unsigned short* pt;
    float2* sums;
    if (bid <= nbN) {
        feat = node_feat; nrows = n_nodes; gofs = 128;
        rbase0 = (bid - 1) * 128; pt = node_pt; sums = node_sums;
    } else {
        feat = edge_feat; nrows = n_edges; gofs = 0;
        rbase0 = (bid - 1 - nbN) * 128; pt = edge_pt; sums = edge_sums;
    }

    __shared__ float gw[DD * HH];  // 32 KB: gamma[d]*W1[d][h] for this half
    for (int i = tid; i < DD * HH; i += 256) {
        int d = i >> 6, h = i & 63;
        gw[i] = gamma[gofs + d] * W1[(gofs + d) * HH + h];
    }
    __syncthreads();

    int hg = tid & 15, rg = tid >> 4;
    int h0 = hg * 4;
    int rbase = rbase0 + rg * 8;

    const float* rp[8];
#pragma unroll
    for (int i = 0; i < 8; ++i) {
        int r = rbase + i;
        r = r < nrows ? r : (nrows - 1);  // clamp loads; writes guarded below
        rp[i] = feat + (size_t)r * DD;
    }

    float acc[8][4];
#pragma unroll
    for (int i = 0; i < 8; ++i)
#pragma unroll
        for (int k = 0; k < 4; ++k) acc[i][k] = 0.f;

    float4 cur[8], nxt[8];
#pragma unroll
    for (int i = 0; i < 8; ++i) cur[i] = *(const float4*)&rp[i][0];

#pragma unroll 2
    for (int d0 = 0; d0 < DD; d0 += 4) {
        // prefetch next d-chunk while computing current
        if (d0 + 4 < DD) {
#pragma unroll
            for (int i = 0; i < 8; ++i) nxt[i] = *(const float4*)&rp[i][d0 + 4];
        }
        float4 g0 = *(const float4*)&gw[(d0 + 0) * HH + h0];
        float4 g1 = *(const float4*)&gw[(d0 + 1) * HH + h0];
        float4 g2 = *(const float4*)&gw[(d0 + 2) * HH + h0];
        float4 g3 = *(const float4*)&gw[(d0 + 3) * HH + h0];
#pragma unroll
        for (int i = 0; i < 8; ++i) {
            float4 a = cur[i];
            acc[i][0] = fmaf(a.x, g0.x, acc[i][0]);
            acc[i][1] = fmaf(a.x, g0.y, acc[i][1]);
            acc[i][2] = fmaf(a.x, g0.z, acc[i][2]);
            acc[i][3] = fmaf(a.x, g0.w, acc[i][3]);
            acc[i][0] = fmaf(a.y, g1.x, acc[i][0]);
            acc[i][1] = fmaf(a.y, g1.y, acc[i][1]);
            acc[i][2] = fmaf(a.y, g1.z, acc[i][2]);
            acc[i][3] = fmaf(a.y, g1.w, acc[i][3]);
            acc[i][0] = fmaf(a.z, g2.x, acc[i][0]);
            acc[i][1] = fmaf(a.z, g2.y, acc[i][1]);
            acc[i][2] = fmaf(a.z, g2.z, acc[i][2]);
            acc[i][3] = fmaf(a.z, g2.w, acc[i][3]);
            acc[i][0] = fmaf(a.w, g3.x, acc[i][0]);
            acc[i][1] = fmaf(a.w, g3.y, acc[i][1]);
            acc[i][2] = fmaf(a.w, g3.z, acc[i][2]);
            acc[i][3] = fmaf(a.w, g3.w, acc[i][3]);
        }
#pragma unroll
        for (int i = 0; i < 8; ++i) cur[i] = nxt[i];
    }

#pragma unroll
    for (int i = 0; i < 8; ++i) {
        int r = rbase + i;
        if (r < nrows) {
            ushort4 st;
            st.x = f2bf(acc[i][0]);
            st.y = f2bf(acc[i][1]);
            st.z = f2bf(acc[i][2]);
            st.w = f2bf(acc[i][3]);
            *(ushort4*)&pt[(size_t)r * HH + h0] = st;
        }
    }

    // ---- phase 2: per-row sum / sumsq (rows hot in L2 from phase 1)
    int l = tid & 15, rg2 = tid >> 4;
#pragma unroll
    for (int k = 0; k < 8; ++k) {
        int r = rbase0 + rg2 + k * 16;
        float s = 0.f, q = 0.f;
        if (r < nrows) {
            const float* fr = feat + (size_t)r * DD;
            float4 a = *(const float4*)&fr[l * 4];
            float4 b = *(const float4*)&fr[64 + l * 4];
            s = a.x + a.y + a.z + a.w + b.x + b.y + b.z + b.w;
            q = a.x * a.x + a.y * a.y + a.z * a.z + a.w * a.w +
                b.x * b.x + b.y * b.y + b.z * b.z + b.w * b.w;
        }
#pragma unroll
        for (int m = 1; m < 16; m <<= 1) {
            s += __shfl_xor(s, m);
            q += __shfl_xor(q, m);
        }
        if (r < nrows && l == 0) sums[r] = make_float2(s, q);
    }
}

// ---------------- per-pair fused LN+MLP via precomputed bf16 tables
// 8 lanes per pair; lane l holds h = 8l..8l+7 (one 16B uint4 = 8 bf16).
__global__ __launch_bounds__(256) void k_pairs(const int* __restrict__ node_idx,
                                               const int* __restrict__ edge_idx,
                                               const unsigned short* __restrict__ node_pt,
                                               const unsigned short* __restrict__ edge_pt,
                                               const float2* __restrict__ node_sums,
                                               const float2* __restrict__ edge_sums,
                                               const float* __restrict__ Gv,
                                               const float* __restrict__ Bv,
                                               const float* __restrict__ W2,
                                               const float* __restrict__ b2,
                                               float* __restrict__ out, int E) {
    int gtid = blockIdx.x * 256 + threadIdx.x;
    int l = gtid & 7;
    int grp = gtid >> 3;
    int ngrps = (gridDim.x * 256) >> 3;

    float G8[8], B8[8], W8[8];
#pragma unroll
    for (int j = 0; j < 8; ++j) {
        G8[j] = Gv[l * 8 + j];
        B8[j] = Bv[l * 8 + j];
        W8[j] = W2[l * 8 + j];
    }
    float b2v = b2[0];

#pragma unroll 2
    for (int p = grp; p < E; p += ngrps) {
        int ni = node_idx[p];
        int ei = edge_idx[p];
        uint4 ue = *(const uint4*)&edge_pt[(size_t)ei * HH + l * 8];
        uint4 un = *(const uint4*)&node_pt[(size_t)ni * HH + l * 8];
        float2 se = edge_sums[ei];
        float2 sn = node_sums[ni];

        float S = se.x + sn.x;
        float Q = se.y + sn.y;
        float mu = S * (1.f / TWO_D);
        float var = fmaf(Q, 1.f / TWO_D, -mu * mu);
        float rstd = rsqrtf(var + LN_EPS);
        float nmu = -mu;

        uint ue_[4] = {ue.x, ue.y, ue.z, ue.w};
        uint un_[4] = {un.x, un.y, un.z, un.w};
        float acc = 0.f;
#pragma unroll
        for (int j = 0; j < 4; ++j) {
            float pe0 = __uint_as_float(ue_[j] << 16);
            float pe1 = __uint_as_float(ue_[j] & 0xFFFF0000u);
            float pn0 = __uint_as_float(un_[j] << 16);
            float pn1 = __uint_as_float(un_[j] & 0xFFFF0000u);
            float t0 = fmaf(nmu, G8[2 * j], pe0 + pn0);
            float v0 = fmaf(rstd, t0, B8[2 * j]);
            v0 = fmaxf(v0, 0.f);
            acc = fmaf(v0, W8[2 * j], acc);
            float t1 = fmaf(nmu, G8[2 * j + 1], pe1 + pn1);
            float v1 = fmaf(rstd, t1, B8[2 * j + 1]);
            v1 = fmaxf(v1, 0.f);
            acc = fmaf(v1, W8[2 * j + 1], acc);
        }

        acc += __shfl_xor(acc, 1);
        acc += __shfl_xor(acc, 2);
        acc += __shfl_xor(acc, 4);

        if (l == 0) out[p] = acc + b2v;
    }
}

extern "C" void kernel_launch(void* const* d_in, const int* in_sizes, int n_in,
                              void* d_out, int out_size, void* d_ws, size_t ws_size,
                              hipStream_t stream) {
    const float* node_feat = (const float*)d_in[0];
    const float* edge_feat = (const float*)d_in[1];
    const float* gamma = (const float*)d_in[2];
    const float* beta = (const float*)d_in[3];
    const float* W1 = (const float*)d_in[4];
    const float* b1 = (const float*)d_in[5];
    const float* W2 = (const float*)d_in[6];
    const float* b2 = (const float*)d_in[7];
    const int* node_idx = (const int*)d_in[8];
    const int* edge_idx = (const int*)d_in[9];

    int n_nodes = in_sizes[0] / DD;
    int n_edges = in_sizes[1] / DD;
    int E = in_sizes[8];

    float* ws = (float*)d_ws;
    float* GB = ws;  // G[64] | B1c[64]
    float2* node_sums = (float2*)(ws + 128);
    float2* edge_sums = node_sums + n_nodes;

    size_t off = 128 + 2 * (size_t)n_nodes + 2 * (size_t)n_edges;
    off = (off + 31) & ~(size_t)31;  // 128B alignment for ptable rows
    unsigned short* node_pt = (unsigned short*)(ws + off);
    unsigned short* edge_pt = node_pt + (size_t)n_nodes * HH;
    // total ws ~= 0.96 MB sums + 15.4 MB tables ~= 16.4 MB

    int nbN = (n_nodes + 127) / 128;
    int nbE = (n_edges + 127) / 128;

    k_fused<<<1 + nbN + nbE, 256, 0, stream>>>(node_feat, n_nodes, nbN,
                                               edge_feat, n_edges,
                                               gamma, beta, W1, b1,
                                               node_pt, node_sums,
                                               edge_pt, edge_sums, GB);
    k_pairs<<<2048, 256, 0, stream>>>(node_idx, edge_idx, node_pt, edge_pt,
                                      node_sums, edge_sums, GB, GB + 64, W2, b2,
                                      (float*)d_out, E);
}

// Round 5
// 55.083 us; speedup vs baseline: 3.2745x; 1.5484x over previous
//
#include <hip/hip_runtime.h>

#define LN_EPS 1e-5f
#define DD 128
#define TWO_D 256
#define HH 64

typedef unsigned int uint;
typedef __attribute__((ext_vector_type(8))) short short8v;   // 8 bf16 (4 VGPRs)
typedef __attribute__((ext_vector_type(4))) float f32x4;     // MFMA accumulator

__device__ __forceinline__ unsigned short f2bf(float f) {
    uint u = __float_as_uint(f);
    u += 0x7FFFu + ((u >> 16) & 1u);  // round-to-nearest-even
    return (unsigned short)(u >> 16);
}
__device__ __forceinline__ float bf2f(unsigned short h) {
    return __uint_as_float(((uint)h) << 16);
}

// ---------------- fused: block 0 = prep (G, B1c); blocks [1,nbN] = node proj;
// blocks (nbN, nbN+nbE] = edge proj. Each proj block: 128 rows via MFMA.
// LDS: [0,32K)  featA bf16 [128 r][128 k], byte = (r*256 + k*2) ^ ((r&7)<<4)
//      [32K,48K) gwB packed frags: byte = (ht*4+ks)*1024 + lane*16 + j*2
//                (after MFMA reused as outB bf16 [128 r][64 h], byte = r*128 + h*2)
__global__ __launch_bounds__(256) void k_fused(
    const float* __restrict__ node_feat, int n_nodes, int nbN,
    const float* __restrict__ edge_feat, int n_edges,
    const float* __restrict__ gamma, const float* __restrict__ beta,
    const float* __restrict__ W1, const float* __restrict__ b1,
    unsigned short* __restrict__ node_pt, float2* __restrict__ node_sums,
    unsigned short* __restrict__ edge_pt, float2* __restrict__ edge_sums,
    float* __restrict__ GB) {
    int bid = blockIdx.x;
    int tid = threadIdx.x;

    if (bid == 0) {
        if (tid < 128) {
            int h = tid & 63;
            bool isB = tid >= 64;
            float acc = isB ? b1[h] : 0.f;
            const float* coef = isB ? beta : gamma;
#pragma unroll 8
            for (int d = 0; d < TWO_D; ++d)
                acc = fmaf(coef[d], W1[d * HH + h], acc);
            GB[tid] = acc;
        }
        return;
    }

    const float* feat;
    int nrows, gofs, rbase0;
    unsigned short* pt;
    float2* sums;
    if (bid <= nbN) {
        feat = node_feat; nrows = n_nodes; gofs = 128;
        rbase0 = (bid - 1) * 128; pt = node_pt; sums = node_sums;
    } else {
        feat = edge_feat; nrows = n_edges; gofs = 0;
        rbase0 = (bid - 1 - nbN) * 128; pt = edge_pt; sums = edge_sums;
    }

    __shared__ __align__(16) char lds[49152];

    // ---- stage gwB in MFMA B-fragment order: B[k][h] = gamma[gofs+k]*W1[gofs+k][h]
    {
        int l = tid & 63;
        int w = tid >> 6;  // 0..3
#pragma unroll
        for (int ci = 0; ci < 4; ++ci) {
            int combo = ci * 4 + w;           // = ht*4 + ks
            int ks = combo & 3;
            int ht = combo >> 2;
            int kbase = gofs + ks * 32 + (l >> 4) * 8;
            int h = ht * 16 + (l & 15);
            unsigned short vals[8];
#pragma unroll
            for (int j = 0; j < 8; ++j)
                vals[j] = f2bf(gamma[kbase + j] * W1[(size_t)(kbase + j) * HH + h]);
            short8v v;
#pragma unroll
            for (int j = 0; j < 8; ++j) v[j] = (short)vals[j];
            *(short8v*)(lds + 32768 + combo * 1024 + l * 16) = v;
        }
    }

    // ---- stage featA: 64KB contiguous f32 -> bf16 LDS tile (burst of 16 dwordx4)
    {
        float4 tmp[16];
#pragma unroll
        for (int u = 0; u < 16; ++u) {
            int F4 = u * 256 + tid;        // float4 index within tile
            int r = F4 >> 5;               // 32 float4 per row
            int rg = rbase0 + r;
            rg = rg < nrows ? rg : (nrows - 1);
            int c4 = (F4 & 31) * 4;        // col in floats
            tmp[u] = *(const float4*)&feat[(size_t)rg * DD + c4];
        }
#pragma unroll
        for (int u = 0; u < 16; ++u) {
            int F4 = u * 256 + tid;
            int r = F4 >> 5;
            int c4 = (F4 & 31) * 4;
            uint2 wv;
            wv.x = (uint)f2bf(tmp[u].x) | ((uint)f2bf(tmp[u].y) << 16);
            wv.y = (uint)f2bf(tmp[u].z) | ((uint)f2bf(tmp[u].w) << 16);
            int byte = (r * 256 + c4 * 2) ^ ((r & 7) << 4);
            *(uint2*)(lds + byte) = wv;
        }
    }

    __syncthreads();

    // ---- MFMA: wave w computes rows [32w, 32w+32) x 64 h
    int w = tid >> 6;
    int lane = tid & 63;
    f32x4 acc[2][4];
#pragma unroll
    for (int i = 0; i < 2; ++i)
#pragma unroll
        for (int j = 0; j < 4; ++j) acc[i][j] = (f32x4){0.f, 0.f, 0.f, 0.f};

    int arow_lo = lane & 15;
    int akofs = (lane >> 4) * 8;
#pragma unroll
    for (int ks = 0; ks < 4; ++ks) {
        int kk = ks * 32 + akofs;
        int rr0 = (2 * w) * 16 + arow_lo;
        int rr1 = rr0 + 16;
        short8v a0 = *(const short8v*)(lds + ((rr0 * 256 + kk * 2) ^ ((rr0 & 7) << 4)));
        short8v a1 = *(const short8v*)(lds + ((rr1 * 256 + kk * 2) ^ ((rr1 & 7) << 4)));
#pragma unroll
        for (int ht = 0; ht < 4; ++ht) {
            short8v b = *(const short8v*)(lds + 32768 + (ht * 4 + ks) * 1024 + lane * 16);
            acc[0][ht] = __builtin_amdgcn_mfma_f32_16x16x32_bf16(a0, b, acc[0][ht], 0, 0, 0);
            acc[1][ht] = __builtin_amdgcn_mfma_f32_16x16x32_bf16(a1, b, acc[1][ht], 0, 0, 0);
        }
    }

    // ---- sums from LDS bf16 tile (2 threads per row)
    {
        int row = tid >> 1, half = tid & 1;
        float s = 0.f, q = 0.f;
#pragma unroll
        for (int i = 0; i < 8; ++i) {
            int byte = (row * 256 + half * 128 + i * 16) ^ ((row & 7) << 4);
            short8v v = *(const short8v*)(lds + byte);
#pragma unroll
            for (int j = 0; j < 8; ++j) {
                float x = bf2f((unsigned short)v[j]);
                s += x;
                q = fmaf(x, x, q);
            }
        }
        s += __shfl_xor(s, 1);
        q += __shfl_xor(q, 1);
        if (half == 0 && rbase0 + row < nrows) sums[rbase0 + row] = make_float2(s, q);
    }

    __syncthreads();  // all waves done reading gwB before overwrite

    // ---- epilogue: acc -> outB (LDS, reusing gwB space), then coalesced store
    {
        unsigned short* ob = (unsigned short*)(lds + 32768);
        int colh = lane & 15;
        int rquad = lane >> 4;
#pragma unroll
        for (int rt = 0; rt < 2; ++rt)
#pragma unroll
            for (int ht = 0; ht < 4; ++ht)
#pragma unroll
                for (int reg = 0; reg < 4; ++reg) {
                    int r = (2 * w + rt) * 16 + rquad * 4 + reg;
                    int h = ht * 16 + colh;
                    ob[r * 64 + h] = f2bf(acc[rt][ht][reg]);
                }
        // wave-local read-back: thread tid reads rows [tid>>1] (own wave's rows)
        int row = tid >> 1;
        if (rbase0 + row < nrows) {
#pragma unroll
            for (int i = 0; i < 4; ++i) {
                short8v v = *(const short8v*)(lds + 32768 + tid * 64 + i * 16);
                *(short8v*)&pt[(size_t)rbase0 * HH + tid * 32 + i * 8] = v;
            }
        }
    }
}

// ---------------- per-pair fused LN+MLP via precomputed bf16 tables
// 8 lanes per pair; lane l holds h = 8l..8l+7 (one 16B uint4 = 8 bf16).
__global__ __launch_bounds__(256) void k_pairs(const int* __restrict__ node_idx,
                                               const int* __restrict__ edge_idx,
                                               const unsigned short* __restrict__ node_pt,
                                               const unsigned short* __restrict__ edge_pt,
                                               const float2* __restrict__ node_sums,
                                               const float2* __restrict__ edge_sums,
                                               const float* __restrict__ Gv,
                                               const float* __restrict__ Bv,
                                               const float* __restrict__ W2,
                                               const float* __restrict__ b2,
                                               float* __restrict__ out, int E) {
    int gtid = blockIdx.x * 256 + threadIdx.x;
    int l = gtid & 7;
    int grp = gtid >> 3;
    int ngrps = (gridDim.x * 256) >> 3;

    float G8[8], B8[8], W8[8];
#pragma unroll
    for (int j = 0; j < 8; ++j) {
        G8[j] = Gv[l * 8 + j];
        B8[j] = Bv[l * 8 + j];
        W8[j] = W2[l * 8 + j];
    }
    float b2v = b2[0];

#pragma unroll 2
    for (int p = grp; p < E; p += ngrps) {
        int ni = node_idx[p];
        int ei = edge_idx[p];
        uint4 ue = *(const uint4*)&edge_pt[(size_t)ei * HH + l * 8];
        uint4 un = *(const uint4*)&node_pt[(size_t)ni * HH + l * 8];
        float2 se = edge_sums[ei];
        float2 sn = node_sums[ni];

        float S = se.x + sn.x;
        float Q = se.y + sn.y;
        float mu = S * (1.f / TWO_D);
        float var = fmaf(Q, 1.f / TWO_D, -mu * mu);
        float rstd = rsqrtf(var + LN_EPS);
        float nmu = -mu;

        uint ue_[4] = {ue.x, ue.y, ue.z, ue.w};
        uint un_[4] = {un.x, un.y, un.z, un.w};
        float acc = 0.f;
#pragma unroll
        for (int j = 0; j < 4; ++j) {
            float pe0 = __uint_as_float(ue_[j] << 16);
            float pe1 = __uint_as_float(ue_[j] & 0xFFFF0000u);
            float pn0 = __uint_as_float(un_[j] << 16);
            float pn1 = __uint_as_float(un_[j] & 0xFFFF0000u);
            float t0 = fmaf(nmu, G8[2 * j], pe0 + pn0);
            float v0 = fmaf(rstd, t0, B8[2 * j]);
            v0 = fmaxf(v0, 0.f);
            acc = fmaf(v0, W8[2 * j], acc);
            float t1 = fmaf(nmu, G8[2 * j + 1], pe1 + pn1);
            float v1 = fmaf(rstd, t1, B8[2 * j + 1]);
            v1 = fmaxf(v1, 0.f);
            acc = fmaf(v1, W8[2 * j + 1], acc);
        }

        acc += __shfl_xor(acc, 1);
        acc += __shfl_xor(acc, 2);
        acc += __shfl_xor(acc, 4);

        if (l == 0) out[p] = acc + b2v;
    }
}

extern "C" void kernel_launch(void* const* d_in, const int* in_sizes, int n_in,
                              void* d_out, int out_size, void* d_ws, size_t ws_size,
                              hipStream_t stream) {
    const float* node_feat = (const float*)d_in[0];
    const float* edge_feat = (const float*)d_in[1];
    const float* gamma = (const float*)d_in[2];
    const float* beta = (const float*)d_in[3];
    const float* W1 = (const float*)d_in[4];
    const float* b1 = (const float*)d_in[5];
    const float* W2 = (const float*)d_in[6];
    const float* b2 = (const float*)d_in[7];
    const int* node_idx = (const int*)d_in[8];
    const int* edge_idx = (const int*)d_in[9];

    int n_nodes = in_sizes[0] / DD;
    int n_edges = in_sizes[1] / DD;
    int E = in_sizes[8];

    float* ws = (float*)d_ws;
    float* GB = ws;  // G[64] | B1c[64]
    float2* node_sums = (float2*)(ws + 128);
    float2* edge_sums = node_sums + n_nodes;

    size_t off = 128 + 2 * (size_t)n_nodes + 2 * (size_t)n_edges;
    off = (off + 31) & ~(size_t)31;  // 128B alignment for ptable rows
    unsigned short* node_pt = (unsigned short*)(ws + off);
    unsigned short* edge_pt = node_pt + (size_t)n_nodes * HH;
    // total ws ~= 0.96 MB sums + 15.4 MB tables ~= 16.4 MB

    int nbN = (n_nodes + 127) / 128;
    int nbE = (n_edges + 127) / 128;

    k_fused<<<1 + nbN + nbE, 256, 0, stream>>>(node_feat, n_nodes, nbN,
                                               edge_feat, n_edges,
                                               gamma, beta, W1, b1,
                                               node_pt, node_sums,
                                               edge_pt, edge_sums, GB);
    k_pairs<<<2048, 256, 0, stream>>>(node_idx, edge_idx, node_pt, edge_pt,
                                      node_sums, edge_sums, GB, GB + 64, W2, b2,
                                      (float*)d_out, E);
}